// Round 5
// baseline (1009.132 us; speedup 1.0000x reference)
//
#include <hip/hip_runtime.h>
#include <hip/hip_bf16.h>

// B=500000, NGI=13, NLOC=10
// diagRAR[b] = (1/dt)*sum_g dw[b,g]*(n[g,:].R)^2
//            + k[b]  *sum_g dw[b,g]*((nx[b,0,g,:].R)^2 + (nx[b,1,g,:].R)^2)
// rr1[b] = r1_1[b] - diagRAR[b]*e_i[b]
//
// Round-3 change: stage nx[b] in register groups of 16 float4 (256 B) so all
// loads covering a 128 B cache line are in flight together -> each HBM line
// fetched once (round-2 counters showed 2.17x over-fetch at VGPR=44).

#define NGI 13
#define NLOC 10
#define PERB (2 * NGI * NLOC) // 260 floats = 65 float4 per b

__global__ __launch_bounds__(256, 4) void diag_rar_kernel(
    const float* __restrict__ e_i,
    const float* __restrict__ r1_1,
    const float* __restrict__ k,
    const float* __restrict__ dt,
    const float* __restrict__ n,
    const float* __restrict__ nx,
    const float* __restrict__ detwei,
    const float* __restrict__ R,
    float* __restrict__ out_diag,
    float* __restrict__ out_rr1,
    int B)
{
    float Rl[NLOC];
#pragma unroll
    for (int i = 0; i < NLOC; ++i) Rl[i] = R[i];

    float nR2[NGI];
#pragma unroll
    for (int g = 0; g < NGI; ++g) {
        float s = 0.f;
#pragma unroll
        for (int i = 0; i < NLOC; ++i) s += n[g * NLOC + i] * Rl[i];
        nR2[g] = s * s;
    }
    const float inv_dt = 1.0f / dt[0];

    for (int b = blockIdx.x * blockDim.x + threadIdx.x; b < B;
         b += gridDim.x * blockDim.x) {
        const float4* __restrict__ nxb =
            reinterpret_cast<const float4*>(nx + (size_t)b * PERB);

        float dot[2][NGI];
#pragma unroll
        for (int c = 0; c < 2; ++c)
#pragma unroll
            for (int g = 0; g < NGI; ++g) dot[c][g] = 0.f;

        // 65 float4 = 4 groups of 16 (256 B, whole cache lines in flight) + 1.
#pragma unroll
        for (int grp = 0; grp < 4; ++grp) {
            float4 v[16];
#pragma unroll
            for (int u = 0; u < 16; ++u) v[u] = nxb[grp * 16 + u];
#pragma unroll
            for (int u = 0; u < 16; ++u) {
                float vv[4] = {v[u].x, v[u].y, v[u].z, v[u].w};
#pragma unroll
                for (int t = 0; t < 4; ++t) {
                    const int flat = (grp * 16 + u) * 4 + t;
                    const int c = flat / (NGI * NLOC);
                    const int rem = flat % (NGI * NLOC);
                    const int g = rem / NLOC;
                    const int i = rem % NLOC;
                    dot[c][g] += vv[t] * Rl[i];
                }
            }
        }
        { // leftover float4 #64 (floats 256..259 -> c=1, g=12, i=6..9)
            float4 v = nxb[64];
            float vv[4] = {v.x, v.y, v.z, v.w};
#pragma unroll
            for (int t = 0; t < 4; ++t) {
                const int flat = 256 + t;
                const int c = flat / (NGI * NLOC);
                const int rem = flat % (NGI * NLOC);
                const int g = rem / NLOC;
                const int i = rem % NLOC;
                dot[c][g] += vv[t] * Rl[i];
            }
        }

        const float* __restrict__ dwp = detwei + (size_t)b * NGI;
        float acc_k = 0.f, acc_n = 0.f;
#pragma unroll
        for (int g = 0; g < NGI; ++g) {
            const float dw = dwp[g];
            acc_k += dw * (dot[0][g] * dot[0][g] + dot[1][g] * dot[1][g]);
            acc_n += dw * nR2[g];
        }

        const float diag = acc_n * inv_dt + k[b] * acc_k;
        out_diag[b] = diag;
        out_rr1[b] = r1_1[b] - diag * e_i[b];
    }
}

extern "C" void kernel_launch(void* const* d_in, const int* in_sizes, int n_in,
                              void* d_out, int out_size, void* d_ws, size_t ws_size,
                              hipStream_t stream) {
    const float* e_i    = (const float*)d_in[0];
    const float* r1_1   = (const float*)d_in[1];
    const float* k      = (const float*)d_in[2];
    const float* dt     = (const float*)d_in[3];
    const float* n      = (const float*)d_in[4];
    const float* nx     = (const float*)d_in[5];
    const float* detwei = (const float*)d_in[6];
    const float* R      = (const float*)d_in[7];

    const int B = in_sizes[0]; // e_i is (B,1)
    float* out_diag = (float*)d_out;
    float* out_rr1  = (float*)d_out + B;

    const int block = 256;
    const int grid = (B + block - 1) / block;
    diag_rar_kernel<<<grid, block, 0, stream>>>(
        e_i, r1_1, k, dt, n, nx, detwei, R, out_diag, out_rr1, B);
}

// Round 7
// 683.429 us; speedup vs baseline: 1.4766x; 1.4766x over previous
//
#include <hip/hip_runtime.h>
#include <hip/hip_bf16.h>

// B=500000, NGI=13, NLOC=10
// diagRAR[b] = (1/dt)*sum_g dw[b,g]*(n[g,:].R)^2
//            + k[b]  *sum_g dw[b,g]*((nx[b,0,g,:].R)^2 + (nx[b,1,g,:].R)^2)
// rr1[b] = r1_1[b] - diagRAR[b]*e_i[b]
//
// Round-6 restructure: coalesced-by-construction loads. Every 5 float4 of nx
// = exactly 2 complete 10-float rows (lcm(4,10)=20). One thread per 5-float4
// group (80 B contiguous; 5 independent loads all in flight together -> each
// 128 B line fetched from HBM exactly once). dot^2 -> LDS; per-b finisher
// does the 13-g weighted sum. Rounds 2/5 showed 2.2-3.0x HBM over-fetch from
// the per-thread-1040B-slab pattern (line reuse across temporally separated
// vmem instrs, evicted by 16 concurrent waves/CU).

#define NGI 13
#define NLOC 10
#define ROWS_PER_B 26          // 2*NGI rows of 10 floats per b
#define GRP_PER_B 13           // 5-float4 groups per b (65 float4 / 5)
#define TILE_B 39              // b's per block
#define LOAD_T (TILE_B * GRP_PER_B)   // 507 loader threads (of 512)
#define BLOCK 512

__global__ __launch_bounds__(BLOCK) void diag_rar_fused(
    const float* __restrict__ e_i,
    const float* __restrict__ r1_1,
    const float* __restrict__ k,
    const float* __restrict__ dt,
    const float* __restrict__ n,
    const float* __restrict__ nx,
    const float* __restrict__ detwei,
    const float* __restrict__ R,
    float* __restrict__ out_diag,
    float* __restrict__ out_rr1,
    int B)
{
    __shared__ float sq[TILE_B][ROWS_PER_B];  // dot^2 per (local b, row)
    __shared__ float dwl[LOAD_T];             // detwei for the tile (39*13)

    const int t = threadIdx.x;
    const long tile_b0 = (long)blockIdx.x * TILE_B;

    // R[0..9] are uniform-address loads -> SGPR broadcast, L1-cached.
    const float R0 = R[0], R1 = R[1], R2 = R[2], R3 = R[3], R4 = R[4];
    const float R5 = R[5], R6 = R[6], R7 = R[7], R8 = R[8], R9 = R[9];

    if (t < LOAD_T) {
        const int lb = t / GRP_PER_B;       // local b: 0..38
        const int u  = t % GRP_PER_B;       // group within b: 0..12
        const long b = tile_b0 + lb;
        if (b < B) {
            // thread t covers float4 indices [tile_b0*65 + 5t, +5): contiguous
            // across the block -> coalesced, lines single-fetch.
            const float4* __restrict__ p =
                reinterpret_cast<const float4*>(nx) + b * 65 + (long)u * 5;
            const float4 v0 = p[0], v1 = p[1], v2 = p[2], v3 = p[3], v4 = p[4];
            // rows 2u (A) and 2u+1 (B) of the 26 rows of this b:
            // A = v0.xyzw v1.xyzw v2.xy ; B = v2.zw v3.xyzw v4.xyzw
            const float dA = v0.x * R0 + v0.y * R1 + v0.z * R2 + v0.w * R3
                           + v1.x * R4 + v1.y * R5 + v1.z * R6 + v1.w * R7
                           + v2.x * R8 + v2.y * R9;
            const float dB = v2.z * R0 + v2.w * R1
                           + v3.x * R2 + v3.y * R3 + v3.z * R4 + v3.w * R5
                           + v4.x * R6 + v4.y * R7 + v4.z * R8 + v4.w * R9;
            *reinterpret_cast<float2*>(&sq[lb][2 * u]) =
                make_float2(dA * dA, dB * dB);
        }
        // coalesced detwei stage: 507 threads == 39 b * 13 g exactly.
        const long dwi = tile_b0 * NGI + t;
        if (dwi < (long)B * NGI) dwl[t] = detwei[dwi];
    }

    __syncthreads();

    if (t < TILE_B) {
        const long b = tile_b0 + t;
        if (b < B) {
            // nR2[g] from uniform-address n,R (SGPR/L1 broadcast).
            float nR2[NGI];
#pragma unroll
            for (int g = 0; g < NGI; ++g) {
                float s = 0.f;
#pragma unroll
                for (int i = 0; i < NLOC; ++i) s += n[g * NLOC + i] * R[i];
                nR2[g] = s * s;
            }
            float acc_k = 0.f, acc_n = 0.f;
#pragma unroll
            for (int g = 0; g < NGI; ++g) {
                const float dw = dwl[t * NGI + g];
                acc_k += dw * (sq[t][g] + sq[t][NGI + g]);
                acc_n += dw * nR2[g];
            }
            const float diag = acc_n * (1.0f / dt[0]) + k[b] * acc_k;
            out_diag[b] = diag;
            out_rr1[b] = r1_1[b] - diag * e_i[b];
        }
    }
}

extern "C" void kernel_launch(void* const* d_in, const int* in_sizes, int n_in,
                              void* d_out, int out_size, void* d_ws, size_t ws_size,
                              hipStream_t stream) {
    const float* e_i    = (const float*)d_in[0];
    const float* r1_1   = (const float*)d_in[1];
    const float* k      = (const float*)d_in[2];
    const float* dt     = (const float*)d_in[3];
    const float* n      = (const float*)d_in[4];
    const float* nx     = (const float*)d_in[5];
    const float* detwei = (const float*)d_in[6];
    const float* R      = (const float*)d_in[7];

    const int B = in_sizes[0]; // e_i is (B,1)
    float* out_diag = (float*)d_out;
    float* out_rr1  = (float*)d_out + B;

    const int grid = (B + TILE_B - 1) / TILE_B; // one tile of 39 b's per block
    diag_rar_fused<<<grid, BLOCK, 0, stream>>>(
        e_i, r1_1, k, dt, n, nx, detwei, R, out_diag, out_rr1, B);
}